// Round 1
// baseline (1646.128 us; speedup 1.0000x reference)
//
#include <hip/hip_runtime.h>
#include <math.h>

#define BB 32
#define TT 24
#define NN 256
#define FF 16
#define HH 128
#define G4 512  // 4*H

__device__ __forceinline__ float sigf(float x) { return 1.f / (1.f + __expf(-x)); }
__device__ __forceinline__ float tanhfast(float x) { return 1.f - 2.f / (__expf(2.f * x) + 1.f); }

// ---------------------------------------------------------------------------
// K1: Ax[b,t,n,f] = sum_j A[b,n,j] * x[b,t,j,f]   (A = adj[:, T-1])
// grid = B*T blocks, 256 threads
// ---------------------------------------------------------------------------
__global__ __launch_bounds__(256) void k1_ax(const float* __restrict__ adj,
                                             const float* __restrict__ x,
                                             float* __restrict__ Ax) {
  const int bt = blockIdx.x;  // b*T + t
  const int b = bt / TT;
  const float* Abase = adj + ((size_t)(b * TT + (TT - 1)) * NN) * NN;
  const float* xbase = x + (size_t)bt * NN * FF;

  __shared__ float x_s[NN * FF];   // [256][16]
  __shared__ float A_s[64 * 65];   // [64 rows][64 j + pad]

  for (int i4 = threadIdx.x; i4 < (NN * FF) / 4; i4 += 256) {
    ((float4*)x_s)[i4] = ((const float4*)xbase)[i4];
  }

  const int rg = threadIdx.x >> 2;  // 0..63 (row within tile)
  const int fg = threadIdx.x & 3;   // 0..3  (f group of 4)

  for (int rt = 0; rt < 4; ++rt) {  // row tiles of 64
    float4 acc = make_float4(0.f, 0.f, 0.f, 0.f);
    for (int jc = 0; jc < 4; ++jc) {  // j chunks of 64
      __syncthreads();
      for (int i = threadIdx.x; i < 64 * 64; i += 256) {
        const int r = i >> 6, j = i & 63;
        A_s[r * 65 + j] = Abase[(size_t)(rt * 64 + r) * NN + jc * 64 + j];
      }
      __syncthreads();
#pragma unroll 8
      for (int j = 0; j < 64; ++j) {
        const float a = A_s[rg * 65 + j];
        const float4 xv = *(const float4*)&x_s[(jc * 64 + j) * FF + fg * 4];
        acc.x += a * xv.x;
        acc.y += a * xv.y;
        acc.z += a * xv.z;
        acc.w += a * xv.w;
      }
    }
    *(float4*)&Ax[((size_t)bt * NN + rt * 64 + rg) * FF + fg * 4] = acc;
  }
}

// ---------------------------------------------------------------------------
// K2 (per time step): for a 32-row tile of (b, n):
//   Ah = A_rows @ h_in[b]                      (32 x 128, K=256)
//   gates = [Ax_t | Ah] @ gcn_W + gcn_b        (32 x 512, K=144)
//   LSTM pointwise: c, h_out
// grid = (8, B), 512 threads. 61KB LDS, phase B overlays phase A staging.
// ---------------------------------------------------------------------------
#define K2_THREADS 512

__global__ __launch_bounds__(K2_THREADS) void k2_step(
    const float* __restrict__ adj, const float* __restrict__ Ax,
    const float* __restrict__ gcnW, const float* __restrict__ gcnb,
    const float* __restrict__ h_in, float* __restrict__ h_out,
    float* __restrict__ cbuf, int t) {
  const int nt = blockIdx.x;  // 0..7
  const int b = blockIdx.y;   // 0..31
  const int n0 = nt * 32;
  const int tid = threadIdx.x;
  const int ty = tid >> 5;  // 0..15 -> rows 2*ty, 2*ty+1
  const int tx = tid & 31;  // 0..31 -> cols 4*tx..4*tx+3

  __shared__ float smem[15296];
  float* Ah_s = smem;                 // [32][149]: cols 0..127 = Ah, 128..143 = Ax rows
  float* A_s = smem + 4768;           // [32][65]   (phase A)
  float* h_s = smem + 4768 + 2080;    // [64][132]  (phase A)
  float* W_s = smem + 4768;           // [16][516]  (phase B overlay)

  const float* Abase = adj + ((size_t)(b * TT + (TT - 1)) * NN + n0) * NN;

  // ---- phase A: Ah = A_rows @ h_in[b] ----
  float4 accA0 = make_float4(0.f, 0.f, 0.f, 0.f);
  float4 accA1 = make_float4(0.f, 0.f, 0.f, 0.f);
  for (int jc = 0; jc < 4; ++jc) {
    __syncthreads();
    for (int i = tid; i < 32 * 64; i += K2_THREADS) {
      const int r = i >> 6, j = i & 63;
      A_s[r * 65 + j] = Abase[(size_t)r * NN + jc * 64 + j];
    }
    for (int i4 = tid; i4 < (64 * HH) / 4; i4 += K2_THREADS) {
      const int j = i4 >> 5, kq = i4 & 31;
      const float4 v = *(const float4*)&h_in[((size_t)b * NN + jc * 64 + j) * HH + kq * 4];
      *(float4*)&h_s[j * 132 + kq * 4] = v;
    }
    __syncthreads();
#pragma unroll 8
    for (int j = 0; j < 64; ++j) {
      const float a0 = A_s[(2 * ty + 0) * 65 + j];
      const float a1 = A_s[(2 * ty + 1) * 65 + j];
      const float4 hv = *(const float4*)&h_s[j * 132 + tx * 4];
      accA0.x += a0 * hv.x; accA0.y += a0 * hv.y; accA0.z += a0 * hv.z; accA0.w += a0 * hv.w;
      accA1.x += a1 * hv.x; accA1.y += a1 * hv.y; accA1.z += a1 * hv.z; accA1.w += a1 * hv.w;
    }
  }
  __syncthreads();
  // store Ah into LDS (scalar stores; row stride 149 keeps b32 reads conflict-free)
  {
    const int r0 = 2 * ty;
    Ah_s[(r0 + 0) * 149 + tx * 4 + 0] = accA0.x;
    Ah_s[(r0 + 0) * 149 + tx * 4 + 1] = accA0.y;
    Ah_s[(r0 + 0) * 149 + tx * 4 + 2] = accA0.z;
    Ah_s[(r0 + 0) * 149 + tx * 4 + 3] = accA0.w;
    Ah_s[(r0 + 1) * 149 + tx * 4 + 0] = accA1.x;
    Ah_s[(r0 + 1) * 149 + tx * 4 + 1] = accA1.y;
    Ah_s[(r0 + 1) * 149 + tx * 4 + 2] = accA1.z;
    Ah_s[(r0 + 1) * 149 + tx * 4 + 3] = accA1.w;
    // stage this tile's Ax rows (32 x 16) at cols 128..143
    const int r = tid >> 4, f = tid & 15;  // 512 threads = 32*16 exactly
    Ah_s[r * 149 + 128 + f] = Ax[((size_t)(b * TT + t) * NN + n0 + r) * FF + f];
  }
  __syncthreads();

  // ---- phase B: gates = [Ah | Ax] @ [Wh ; Wx], K=144 in 9 chunks of 16 ----
  float4 acc[2][4];
#pragma unroll
  for (int i = 0; i < 2; ++i)
#pragma unroll
    for (int cb = 0; cb < 4; ++cb) acc[i][cb] = make_float4(0.f, 0.f, 0.f, 0.f);

  for (int kc = 0; kc < 9; ++kc) {
    for (int i4 = tid; i4 < (16 * G4) / 4; i4 += K2_THREADS) {
      const int kk = i4 >> 7, cq = i4 & 127;
      const int wrow = (kc < 8) ? (FF + kc * 16 + kk) : kk;  // gcn_W rows: 0..15=Wx, 16..143=Wh
      const float4 v = *(const float4*)&gcnW[(size_t)wrow * G4 + cq * 4];
      *(float4*)&W_s[kk * 516 + cq * 4] = v;
    }
    __syncthreads();
#pragma unroll
    for (int kk = 0; kk < 16; ++kk) {
      const int k = kc * 16 + kk;
      const float a0 = Ah_s[(2 * ty + 0) * 149 + k];
      const float a1 = Ah_s[(2 * ty + 1) * 149 + k];
#pragma unroll
      for (int cb = 0; cb < 4; ++cb) {
        const float4 w = *(const float4*)&W_s[kk * 516 + cb * 128 + tx * 4];
        acc[0][cb].x += a0 * w.x; acc[0][cb].y += a0 * w.y;
        acc[0][cb].z += a0 * w.z; acc[0][cb].w += a0 * w.w;
        acc[1][cb].x += a1 * w.x; acc[1][cb].y += a1 * w.y;
        acc[1][cb].z += a1 * w.z; acc[1][cb].w += a1 * w.w;
      }
    }
    __syncthreads();
  }

  // ---- epilogue: LSTM pointwise ----
  const float4 bi = *(const float4*)&gcnb[0 * HH + tx * 4];
  const float4 bf = *(const float4*)&gcnb[1 * HH + tx * 4];
  const float4 bg = *(const float4*)&gcnb[2 * HH + tx * 4];
  const float4 bo = *(const float4*)&gcnb[3 * HH + tx * 4];
#pragma unroll
  for (int i = 0; i < 2; ++i) {
    const int n = n0 + 2 * ty + i;
    const size_t off = ((size_t)b * NN + n) * HH + tx * 4;
    float4 cv = *(const float4*)&cbuf[off];
    float4 cnew, hnew;
    {
      const float iv = sigf(acc[i][0].x + bi.x), fv = sigf(acc[i][1].x + bf.x);
      const float gv = tanhfast(acc[i][2].x + bg.x), ov = sigf(acc[i][3].x + bo.x);
      const float cn = fv * cv.x + iv * gv;
      cnew.x = cn; hnew.x = ov * tanhfast(cn);
    }
    {
      const float iv = sigf(acc[i][0].y + bi.y), fv = sigf(acc[i][1].y + bf.y);
      const float gv = tanhfast(acc[i][2].y + bg.y), ov = sigf(acc[i][3].y + bo.y);
      const float cn = fv * cv.y + iv * gv;
      cnew.y = cn; hnew.y = ov * tanhfast(cn);
    }
    {
      const float iv = sigf(acc[i][0].z + bi.z), fv = sigf(acc[i][1].z + bf.z);
      const float gv = tanhfast(acc[i][2].z + bg.z), ov = sigf(acc[i][3].z + bo.z);
      const float cn = fv * cv.z + iv * gv;
      cnew.z = cn; hnew.z = ov * tanhfast(cn);
    }
    {
      const float iv = sigf(acc[i][0].w + bi.w), fv = sigf(acc[i][1].w + bf.w);
      const float gv = tanhfast(acc[i][2].w + bg.w), ov = sigf(acc[i][3].w + bo.w);
      const float cn = fv * cv.w + iv * gv;
      cnew.w = cn; hnew.w = ov * tanhfast(cn);
    }
    *(float4*)&cbuf[off] = cnew;
    *(float4*)&h_out[off] = hnew;
  }
}

// ---------------------------------------------------------------------------
// Tail: GRU over t (per-batch independent) + x_spatial(fc5) + fc2/fc3/fc4.
// grid = B blocks, 384 threads (one per gate row).
// ---------------------------------------------------------------------------
__global__ __launch_bounds__(384) void k_tail(
    const float* __restrict__ x, const float* __restrict__ hfin,
    const int* __restrict__ tsi_p, const float* __restrict__ gruWih,
    const float* __restrict__ gruWhh, const float* __restrict__ gru_bih,
    const float* __restrict__ gru_bhh, const float* __restrict__ fc2W,
    const float* __restrict__ fc2b, const float* __restrict__ fc3W,
    const float* __restrict__ fc3b, const float* __restrict__ fc4W,
    const float* __restrict__ fc4b, const float* __restrict__ fc5W,
    const float* __restrict__ fc5b, float* __restrict__ out) {
  const int b = blockIdx.x;
  const int m = threadIdx.x;  // 0..383
  const int tsi = tsi_p[0];

  __shared__ float Wih_s[384 * 17];
  __shared__ float h_s[HH];
  __shared__ float xt_s[FF];
  __shared__ float gi_s[384];
  __shared__ float gh_s[384];
  __shared__ float hc_s[2 * HH];
  __shared__ float xr_s[HH];
  __shared__ float f2_s[HH];
  __shared__ float f3_s[64];

  for (int i = m; i < 384 * FF; i += 384) {
    const int r = i >> 4, f = i & 15;
    Wih_s[r * 17 + f] = gruWih[i];
  }
  const float bih_r = gru_bih[m];
  const float bhh_r = gru_bhh[m];
  if (m < HH) h_s[m] = 0.f;

  for (int t = 0; t < TT; ++t) {
    if (m < FF) xt_s[m] = x[(((size_t)b * TT + t) * NN + tsi) * FF + m];
    __syncthreads();  // xt ready; h_s stable; (t=0: Wih_s/h_s init ready)
    float gi = bih_r;
#pragma unroll
    for (int f = 0; f < FF; ++f) gi += xt_s[f] * Wih_s[m * 17 + f];
    float gh = bhh_r;
    const float* wr = gruWhh + (size_t)m * HH;
#pragma unroll 8
    for (int k = 0; k < HH; k += 4) {
      const float4 w = *(const float4*)(wr + k);
      gh += h_s[k] * w.x + h_s[k + 1] * w.y + h_s[k + 2] * w.z + h_s[k + 3] * w.w;
    }
    gi_s[m] = gi;
    gh_s[m] = gh;
    __syncthreads();  // gi/gh ready; all h_s reads done
    float hnew = 0.f;
    if (m < HH) {
      const float r = sigf(gi_s[m] + gh_s[m]);
      const float z = sigf(gi_s[HH + m] + gh_s[HH + m]);
      const float nn = tanhfast(gi_s[2 * HH + m] + r * gh_s[2 * HH + m]);
      hnew = (1.f - z) * nn + z * h_s[m];
    }
    __syncthreads();  // all gi_s/gh_s/h_s reads done before overwrite
    if (m < HH) h_s[m] = hnew;
  }
  __syncthreads();

  // x_spatial = relu(hfin[b, tsi, :]) @ fc5_W^T + fc5_b ; hc = [h_gru | x_spatial]
  if (m < HH) {
    hc_s[m] = h_s[m];
    xr_s[m] = fmaxf(hfin[((size_t)b * NN + tsi) * HH + m], 0.f);
  }
  __syncthreads();
  if (m < HH) {
    float v = fc5b[m];
    const float* wr = fc5W + (size_t)m * HH;
#pragma unroll 8
    for (int k = 0; k < HH; k += 4) {
      const float4 w = *(const float4*)(wr + k);
      v += xr_s[k] * w.x + xr_s[k + 1] * w.y + xr_s[k + 2] * w.z + xr_s[k + 3] * w.w;
    }
    hc_s[HH + m] = v;
  }
  __syncthreads();
  if (m < HH) {
    float v = fc2b[m];
    const float* wr = fc2W + (size_t)m * 2 * HH;
#pragma unroll 8
    for (int k = 0; k < 2 * HH; k += 4) {
      const float4 w = *(const float4*)(wr + k);
      v += hc_s[k] * w.x + hc_s[k + 1] * w.y + hc_s[k + 2] * w.z + hc_s[k + 3] * w.w;
    }
    f2_s[m] = fmaxf(v, 0.f);
  }
  __syncthreads();
  if (m < 64) {
    float v = fc3b[m];
    const float* wr = fc3W + (size_t)m * HH;
#pragma unroll 8
    for (int k = 0; k < HH; k += 4) {
      const float4 w = *(const float4*)(wr + k);
      v += f2_s[k] * w.x + f2_s[k + 1] * w.y + f2_s[k + 2] * w.z + f2_s[k + 3] * w.w;
    }
    f3_s[m] = fmaxf(v, 0.f);
  }
  __syncthreads();
  if (m < 24) {
    float v = fc4b[m];
    const float* wr = fc4W + (size_t)m * 64;
#pragma unroll
    for (int k = 0; k < 64; k += 4) {
      const float4 w = *(const float4*)(wr + k);
      v += f3_s[k] * w.x + f3_s[k + 1] * w.y + f3_s[k + 2] * w.z + f3_s[k + 3] * w.w;
    }
    out[b * 24 + m] = v;
  }
}

// ---------------------------------------------------------------------------
extern "C" void kernel_launch(void* const* d_in, const int* in_sizes, int n_in,
                              void* d_out, int out_size, void* d_ws, size_t ws_size,
                              hipStream_t stream) {
  const float* x = (const float*)d_in[0];
  const float* adj = (const float*)d_in[1];
  const int* tsi = (const int*)d_in[2];
  const float* gcnW = (const float*)d_in[3];
  const float* gcnb = (const float*)d_in[4];
  const float* gruWih = (const float*)d_in[5];
  const float* gruWhh = (const float*)d_in[6];
  const float* gru_bih = (const float*)d_in[7];
  const float* gru_bhh = (const float*)d_in[8];
  const float* fc2W = (const float*)d_in[9];
  const float* fc2b = (const float*)d_in[10];
  const float* fc3W = (const float*)d_in[11];
  const float* fc3b = (const float*)d_in[12];
  const float* fc4W = (const float*)d_in[13];
  const float* fc4b = (const float*)d_in[14];
  const float* fc5W = (const float*)d_in[15];
  const float* fc5b = (const float*)d_in[16];
  float* out = (float*)d_out;

  float* Ax = (float*)d_ws;                          // B*T*N*F
  float* hbuf0 = Ax + (size_t)BB * TT * NN * FF;     // B*N*H
  float* cbuf = hbuf0 + (size_t)BB * NN * HH;        // B*N*H
  float* hbuf1 = cbuf + (size_t)BB * NN * HH;        // B*N*H

  // zero h0 and c (adjacent) — ws is poisoned 0xAA before every call
  hipMemsetAsync(hbuf0, 0, (size_t)2 * BB * NN * HH * sizeof(float), stream);

  k1_ax<<<dim3(BB * TT), 256, 0, stream>>>(adj, x, Ax);

  for (int t = 0; t < TT; ++t) {
    const float* hin = (t & 1) ? hbuf1 : hbuf0;
    float* hout = (t & 1) ? hbuf0 : hbuf1;
    k2_step<<<dim3(8, BB), K2_THREADS, 0, stream>>>(adj, Ax, gcnW, gcnb, hin, hout, cbuf, t);
  }
  // T=24 even: final h is in hbuf0
  k_tail<<<dim3(BB), 384, 0, stream>>>(x, hbuf0, tsi, gruWih, gruWhh, gru_bih, gru_bhh,
                                       fc2W, fc2b, fc3W, fc3b, fc4W, fc4b, fc5W, fc5b, out);
}

// Round 2
// 1275.755 us; speedup vs baseline: 1.2903x; 1.2903x over previous
//
#include <hip/hip_runtime.h>
#include <math.h>

#define BB 32
#define TT 24
#define NN 256
#define FF 16
#define HH 128
#define G4 512  // 4*H

__device__ __forceinline__ float sigf(float x) { return 1.f / (1.f + __expf(-x)); }
__device__ __forceinline__ float tanhfast(float x) { return 1.f - 2.f / (__expf(2.f * x) + 1.f); }

// Stage nfloats (multiple of 256) from g to LDS l via global_load_lds width=16.
// Each call moves 256 floats: lane i writes l + call*256 + i*4  <- g + call*256 + i*4.
__device__ __forceinline__ void stage_region(const float* __restrict__ g, float* l,
                                             int nfloats, int wv, int lane) {
  const int ncalls = nfloats >> 8;
  for (int i = wv; i < ncalls; i += 4) {
    __builtin_amdgcn_global_load_lds(
        (const __attribute__((address_space(1))) void*)(g + i * 256 + lane * 4),
        (__attribute__((address_space(3))) void*)(l + i * 256), 16, 0, 0);
  }
}

// ---------------------------------------------------------------------------
// K1: Ax[b,t,n,f] = sum_j A[b,n,j] * x[b,t,j,f]   (A = adj[:, T-1])
// grid = B*T blocks, 256 threads
// ---------------------------------------------------------------------------
__global__ __launch_bounds__(256) void k1_ax(const float* __restrict__ adj,
                                             const float* __restrict__ x,
                                             float* __restrict__ Ax) {
  const int bt = blockIdx.x;  // b*T + t
  const int b = bt / TT;
  const float* Abase = adj + ((size_t)(b * TT + (TT - 1)) * NN) * NN;
  const float* xbase = x + (size_t)bt * NN * FF;

  __shared__ float x_s[NN * FF];   // [256][16]
  __shared__ float A_s[64 * 65];   // [64 rows][64 j + pad]

  for (int i4 = threadIdx.x; i4 < (NN * FF) / 4; i4 += 256) {
    ((float4*)x_s)[i4] = ((const float4*)xbase)[i4];
  }

  const int rg = threadIdx.x >> 2;  // 0..63 (row within tile)
  const int fg = threadIdx.x & 3;   // 0..3  (f group of 4)

  for (int rt = 0; rt < 4; ++rt) {  // row tiles of 64
    float4 acc = make_float4(0.f, 0.f, 0.f, 0.f);
    for (int jc = 0; jc < 4; ++jc) {  // j chunks of 64
      __syncthreads();
      for (int i = threadIdx.x; i < 64 * 64; i += 256) {
        const int r = i >> 6, j = i & 63;
        A_s[r * 65 + j] = Abase[(size_t)(rt * 64 + r) * NN + jc * 64 + j];
      }
      __syncthreads();
#pragma unroll 8
      for (int j = 0; j < 64; ++j) {
        const float a = A_s[rg * 65 + j];
        const float4 xv = *(const float4*)&x_s[(jc * 64 + j) * FF + fg * 4];
        acc.x += a * xv.x;
        acc.y += a * xv.y;
        acc.z += a * xv.z;
        acc.w += a * xv.w;
      }
    }
    *(float4*)&Ax[((size_t)bt * NN + rt * 64 + rg) * FF + fg * 4] = acc;
  }
}

// ---------------------------------------------------------------------------
// K2 (per time step), 256 threads, grid (8 ntiles, B):
//   phase A: Ah(32x128) = A_rows(32x256) @ h_in[b](256x128)
//            A read from GLOBAL (broadcast within row-group), h from LDS
//            (staged via global_load_lds, unpadded so layout is legal),
//            4x4 register tile.
//   phase B: gates(32x512) = [Ah|Ax](32x144) @ W(144x512), 8x8 register tile;
//            Ah operand is wave-uniform broadcast (wave = one row-group),
//            W staged 48 rows at a time via global_load_lds.
//   epilogue: gates -> LDS -> LSTM pointwise -> c, h_out.
// LDS: region1 = 48*512 floats (96KB, overlaid h_s / W_s / gates_s)
//      Ah_s    = 32*144 floats (18KB)
// ---------------------------------------------------------------------------
#define K2_THR 256

__global__ __launch_bounds__(K2_THR) void k2_step(
    const float* __restrict__ adj, const float* __restrict__ Ax,
    const float* __restrict__ gcnW, const float* __restrict__ gcnb,
    const float* __restrict__ h_in, float* __restrict__ h_out,
    float* __restrict__ cbuf, int t) {
  const int nt = blockIdx.x;  // 0..7
  const int b = blockIdx.y;   // 0..31
  const int n0 = nt * 32;
  const int tid = threadIdx.x;
  const int lane = tid & 63;
  const int wv = tid >> 6;

  __shared__ float region1[48 * 512];  // 96KB: h_s (64KB) / W_s (96KB) / gates_s (64KB)
  __shared__ float Ah_s[32 * 144];     // cols 0..127 = Ah, 128..143 = Ax
  float* h_s = region1;  // [128 nodes][128] unpadded
  float* W_s = region1;  // [48 k][512] unpadded
  float* g_s = region1;  // [32 n][512] unpadded

  // ---- stage Ax rows for this tile into Ah_s cols 128..143 (512 floats) ----
  {
    const int r = tid >> 3, f = (tid & 7) * 2;
    const float2 v = *(const float2*)&Ax[((size_t)(b * TT + t) * NN + n0 + r) * FF + f];
    *(float2*)&Ah_s[r * 144 + 128 + f] = v;
  }

  // ---- phase A: 8 rowgroups x 32 colgroups, 4x4 tile ----
  const int rgA = tid >> 5;         // 0..7 -> rows rgA*4..+3
  const int cA = (tid & 31) * 4;    // col base (h dim)
  float4 accA[4];
#pragma unroll
  for (int r = 0; r < 4; ++r) accA[r] = make_float4(0.f, 0.f, 0.f, 0.f);

  const float* Abase = adj + ((size_t)(b * TT + (TT - 1)) * NN + n0) * NN;

  for (int jc = 0; jc < 2; ++jc) {  // two 128-node chunks of h
    // stage h chunk: 128*128 floats contiguous
    stage_region(h_in + ((size_t)b * NN + jc * 128) * HH, h_s, 128 * HH, wv, lane);
    __syncthreads();  // (covers Ax ds_writes on jc=0, and vmcnt for h)

    const float* Ar0 = Abase + (size_t)(rgA * 4 + 0) * NN + jc * 128;
    const float* Ar1 = Abase + (size_t)(rgA * 4 + 1) * NN + jc * 128;
    const float* Ar2 = Abase + (size_t)(rgA * 4 + 2) * NN + jc * 128;
    const float* Ar3 = Abase + (size_t)(rgA * 4 + 3) * NN + jc * 128;
#pragma unroll 4
    for (int j4 = 0; j4 < 128; j4 += 4) {
      const float4 a0 = *(const float4*)(Ar0 + j4);
      const float4 a1 = *(const float4*)(Ar1 + j4);
      const float4 a2 = *(const float4*)(Ar2 + j4);
      const float4 a3 = *(const float4*)(Ar3 + j4);
      float4 hv[4];
#pragma unroll
      for (int d = 0; d < 4; ++d) hv[d] = *(const float4*)&h_s[(j4 + d) * HH + cA];
#pragma unroll
      for (int d = 0; d < 4; ++d) {
        const float s0 = d == 0 ? a0.x : (d == 1 ? a0.y : (d == 2 ? a0.z : a0.w));
        const float s1 = d == 0 ? a1.x : (d == 1 ? a1.y : (d == 2 ? a1.z : a1.w));
        const float s2 = d == 0 ? a2.x : (d == 1 ? a2.y : (d == 2 ? a2.z : a2.w));
        const float s3 = d == 0 ? a3.x : (d == 1 ? a3.y : (d == 2 ? a3.z : a3.w));
        accA[0].x += s0 * hv[d].x; accA[0].y += s0 * hv[d].y; accA[0].z += s0 * hv[d].z; accA[0].w += s0 * hv[d].w;
        accA[1].x += s1 * hv[d].x; accA[1].y += s1 * hv[d].y; accA[1].z += s1 * hv[d].z; accA[1].w += s1 * hv[d].w;
        accA[2].x += s2 * hv[d].x; accA[2].y += s2 * hv[d].y; accA[2].z += s2 * hv[d].z; accA[2].w += s2 * hv[d].w;
        accA[3].x += s3 * hv[d].x; accA[3].y += s3 * hv[d].y; accA[3].z += s3 * hv[d].z; accA[3].w += s3 * hv[d].w;
      }
    }
    __syncthreads();  // h_s reads done before restage/overlay
  }
  // write Ah into Ah_s
#pragma unroll
  for (int r = 0; r < 4; ++r) {
    *(float4*)&Ah_s[(rgA * 4 + r) * 144 + cA] = accA[r];
  }

  // ---- phase B: 4 rowgroups(=waves) x 64 colgroups, 8x8 tile ----
  const int rB = (tid >> 6) * 8;   // wave-uniform row base -> Ah broadcast
  const int cB = (tid & 63) * 8;   // col base
  float4 acc[8][2];
#pragma unroll
  for (int r = 0; r < 8; ++r) {
    acc[r][0] = make_float4(0.f, 0.f, 0.f, 0.f);
    acc[r][1] = make_float4(0.f, 0.f, 0.f, 0.f);
  }

  for (int wc = 0; wc < 3; ++wc) {
    __syncthreads();  // prev W_s/h_s reads done (wc=0: doubles as Ah-ready barrier)
    if (wc < 2) {
      // k in [wc*48, wc*48+48) -> gcn_W rows 16 + wc*48 .. +48 (contiguous)
      stage_region(gcnW + (size_t)(16 + wc * 48) * G4, W_s, 48 * G4, wv, lane);
    } else {
      // k 96..127 -> rows 112..143 ; k 128..143 -> rows 0..15
      stage_region(gcnW + (size_t)112 * G4, W_s, 32 * G4, wv, lane);
      stage_region(gcnW, W_s + 32 * G4, 16 * G4, wv, lane);
    }
    __syncthreads();

    const int k0 = wc * 48;
#pragma unroll 3
    for (int kk = 0; kk < 48; kk += 4) {
      float4 ah[8];
#pragma unroll
      for (int r = 0; r < 8; ++r) ah[r] = *(const float4*)&Ah_s[(rB + r) * 144 + k0 + kk];
      float4 w0[4], w1[4];
#pragma unroll
      for (int d = 0; d < 4; ++d) {
        w0[d] = *(const float4*)&W_s[(kk + d) * G4 + cB];
        w1[d] = *(const float4*)&W_s[(kk + d) * G4 + cB + 4];
      }
#pragma unroll
      for (int r = 0; r < 8; ++r) {
#pragma unroll
        for (int d = 0; d < 4; ++d) {
          const float s = d == 0 ? ah[r].x : (d == 1 ? ah[r].y : (d == 2 ? ah[r].z : ah[r].w));
          acc[r][0].x += s * w0[d].x; acc[r][0].y += s * w0[d].y;
          acc[r][0].z += s * w0[d].z; acc[r][0].w += s * w0[d].w;
          acc[r][1].x += s * w1[d].x; acc[r][1].y += s * w1[d].y;
          acc[r][1].z += s * w1[d].z; acc[r][1].w += s * w1[d].w;
        }
      }
    }
  }
  __syncthreads();  // last W reads done -> overlay with gates
#pragma unroll
  for (int r = 0; r < 8; ++r) {
    *(float4*)&g_s[(rB + r) * G4 + cB] = acc[r][0];
    *(float4*)&g_s[(rB + r) * G4 + cB + 4] = acc[r][1];
  }
  __syncthreads();

  // ---- epilogue: LSTM pointwise. thread -> 4 rows x 4 h-cols ----
  const int tc = (tid & 31) * 4;   // h col base
  const int r0e = (tid >> 5) * 4;  // row base
  const float4 bi = *(const float4*)&gcnb[0 * HH + tc];
  const float4 bf = *(const float4*)&gcnb[1 * HH + tc];
  const float4 bg = *(const float4*)&gcnb[2 * HH + tc];
  const float4 bo = *(const float4*)&gcnb[3 * HH + tc];
#pragma unroll
  for (int rr = 0; rr < 4; ++rr) {
    const int r = r0e + rr;
    const float4 gi_ = *(const float4*)&g_s[r * G4 + 0 * HH + tc];
    const float4 gf_ = *(const float4*)&g_s[r * G4 + 1 * HH + tc];
    const float4 gg_ = *(const float4*)&g_s[r * G4 + 2 * HH + tc];
    const float4 go_ = *(const float4*)&g_s[r * G4 + 3 * HH + tc];
    const size_t off = ((size_t)b * NN + n0 + r) * HH + tc;
    float4 cv = *(const float4*)&cbuf[off];
    float4 cnew, hnew;
    {
      const float iv = sigf(gi_.x + bi.x), fv = sigf(gf_.x + bf.x);
      const float gv = tanhfast(gg_.x + bg.x), ov = sigf(go_.x + bo.x);
      const float cn = fv * cv.x + iv * gv;
      cnew.x = cn; hnew.x = ov * tanhfast(cn);
    }
    {
      const float iv = sigf(gi_.y + bi.y), fv = sigf(gf_.y + bf.y);
      const float gv = tanhfast(gg_.y + bg.y), ov = sigf(go_.y + bo.y);
      const float cn = fv * cv.y + iv * gv;
      cnew.y = cn; hnew.y = ov * tanhfast(cn);
    }
    {
      const float iv = sigf(gi_.z + bi.z), fv = sigf(gf_.z + bf.z);
      const float gv = tanhfast(gg_.z + bg.z), ov = sigf(go_.z + bo.z);
      const float cn = fv * cv.z + iv * gv;
      cnew.z = cn; hnew.z = ov * tanhfast(cn);
    }
    {
      const float iv = sigf(gi_.w + bi.w), fv = sigf(gf_.w + bf.w);
      const float gv = tanhfast(gg_.w + bg.w), ov = sigf(go_.w + bo.w);
      const float cn = fv * cv.w + iv * gv;
      cnew.w = cn; hnew.w = ov * tanhfast(cn);
    }
    *(float4*)&cbuf[off] = cnew;
    *(float4*)&h_out[off] = hnew;
  }
}

// ---------------------------------------------------------------------------
// Tail: GRU over t + x_spatial(fc5) + fc2/fc3/fc4.
// grid = B blocks, 384 threads. Whh row m held in 32 float4 registers.
// ---------------------------------------------------------------------------
__global__ __launch_bounds__(384) void k_tail(
    const float* __restrict__ x, const float* __restrict__ hfin,
    const int* __restrict__ tsi_p, const float* __restrict__ gruWih,
    const float* __restrict__ gruWhh, const float* __restrict__ gru_bih,
    const float* __restrict__ gru_bhh, const float* __restrict__ fc2W,
    const float* __restrict__ fc2b, const float* __restrict__ fc3W,
    const float* __restrict__ fc3b, const float* __restrict__ fc4W,
    const float* __restrict__ fc4b, const float* __restrict__ fc5W,
    const float* __restrict__ fc5b, float* __restrict__ out) {
  const int b = blockIdx.x;
  const int m = threadIdx.x;  // 0..383
  const int tsi = tsi_p[0];

  __shared__ float h_s[HH];
  __shared__ float xts[TT * FF];  // [24][16]
  __shared__ float sum_s[384];    // gi+gh
  __shared__ float gh_s[384];
  __shared__ float hc_s[2 * HH];
  __shared__ float xr_s[HH];
  __shared__ float f2_s[HH];
  __shared__ float f3_s[64];

  // per-thread weight rows in registers
  float4 whh[32];
#pragma unroll
  for (int q = 0; q < 32; ++q) whh[q] = *(const float4*)&gruWhh[(size_t)m * HH + q * 4];
  float4 wih[4];
#pragma unroll
  for (int q = 0; q < 4; ++q) wih[q] = *(const float4*)&gruWih[(size_t)m * FF + q * 4];
  const float bih_r = gru_bih[m];
  const float bhh_r = gru_bhh[m];

  {  // stage x[b, :, tsi, :]
    const int t = m >> 4, f = m & 15;
    xts[m] = x[(((size_t)b * TT + t) * NN + tsi) * FF + f];
  }
  if (m < HH) h_s[m] = 0.f;
  __syncthreads();

  for (int t = 0; t < TT; ++t) {
    float gi = bih_r;
#pragma unroll
    for (int q = 0; q < 4; ++q) {
      const float4 xv = *(const float4*)&xts[t * FF + q * 4];  // broadcast
      gi += wih[q].x * xv.x + wih[q].y * xv.y + wih[q].z * xv.z + wih[q].w * xv.w;
    }
    float gh = bhh_r;
#pragma unroll
    for (int q = 0; q < 32; ++q) {
      const float4 hv = *(const float4*)&h_s[q * 4];  // broadcast
      gh += whh[q].x * hv.x + whh[q].y * hv.y + whh[q].z * hv.z + whh[q].w * hv.w;
    }
    sum_s[m] = gi + gh;
    gh_s[m] = gh;
    __syncthreads();
    float hnew = 0.f;
    if (m < HH) {
      const float r = sigf(sum_s[m]);
      const float z = sigf(sum_s[HH + m]);
      const float ghn = gh_s[2 * HH + m];
      const float nn = tanhfast(sum_s[2 * HH + m] - ghn + r * ghn);
      hnew = (1.f - z) * nn + z * h_s[m];
    }
    __syncthreads();  // all h_s / sum_s reads done
    if (m < HH) h_s[m] = hnew;
    __syncthreads();  // h_s visible for next step
  }

  // x_spatial = relu(hfin[b, tsi, :]) @ fc5_W^T + fc5_b ; hc = [h_gru | x_spatial]
  if (m < HH) {
    hc_s[m] = h_s[m];
    xr_s[m] = fmaxf(hfin[((size_t)b * NN + tsi) * HH + m], 0.f);
  }
  __syncthreads();
  if (m < HH) {
    float v = fc5b[m];
    const float* wr = fc5W + (size_t)m * HH;
#pragma unroll 8
    for (int k = 0; k < HH; k += 4) {
      const float4 w = *(const float4*)(wr + k);
      v += xr_s[k] * w.x + xr_s[k + 1] * w.y + xr_s[k + 2] * w.z + xr_s[k + 3] * w.w;
    }
    hc_s[HH + m] = v;
  }
  __syncthreads();
  if (m < HH) {
    float v = fc2b[m];
    const float* wr = fc2W + (size_t)m * 2 * HH;
#pragma unroll 8
    for (int k = 0; k < 2 * HH; k += 4) {
      const float4 w = *(const float4*)(wr + k);
      v += hc_s[k] * w.x + hc_s[k + 1] * w.y + hc_s[k + 2] * w.z + hc_s[k + 3] * w.w;
    }
    f2_s[m] = fmaxf(v, 0.f);
  }
  __syncthreads();
  if (m < 64) {
    float v = fc3b[m];
    const float* wr = fc3W + (size_t)m * HH;
#pragma unroll 8
    for (int k = 0; k < HH; k += 4) {
      const float4 w = *(const float4*)(wr + k);
      v += f2_s[k] * w.x + f2_s[k + 1] * w.y + f2_s[k + 2] * w.z + f2_s[k + 3] * w.w;
    }
    f3_s[m] = fmaxf(v, 0.f);
  }
  __syncthreads();
  if (m < 24) {
    float v = fc4b[m];
    const float* wr = fc4W + (size_t)m * 64;
#pragma unroll
    for (int k = 0; k < 64; k += 4) {
      const float4 w = *(const float4*)(wr + k);
      v += f3_s[k] * w.x + f3_s[k + 1] * w.y + f3_s[k + 2] * w.z + f3_s[k + 3] * w.w;
    }
    out[b * 24 + m] = v;
  }
}

// ---------------------------------------------------------------------------
extern "C" void kernel_launch(void* const* d_in, const int* in_sizes, int n_in,
                              void* d_out, int out_size, void* d_ws, size_t ws_size,
                              hipStream_t stream) {
  const float* x = (const float*)d_in[0];
  const float* adj = (const float*)d_in[1];
  const int* tsi = (const int*)d_in[2];
  const float* gcnW = (const float*)d_in[3];
  const float* gcnb = (const float*)d_in[4];
  const float* gruWih = (const float*)d_in[5];
  const float* gruWhh = (const float*)d_in[6];
  const float* gru_bih = (const float*)d_in[7];
  const float* gru_bhh = (const float*)d_in[8];
  const float* fc2W = (const float*)d_in[9];
  const float* fc2b = (const float*)d_in[10];
  const float* fc3W = (const float*)d_in[11];
  const float* fc3b = (const float*)d_in[12];
  const float* fc4W = (const float*)d_in[13];
  const float* fc4b = (const float*)d_in[14];
  const float* fc5W = (const float*)d_in[15];
  const float* fc5b = (const float*)d_in[16];
  float* out = (float*)d_out;

  float* Ax = (float*)d_ws;                          // B*T*N*F
  float* hbuf0 = Ax + (size_t)BB * TT * NN * FF;     // B*N*H
  float* cbuf = hbuf0 + (size_t)BB * NN * HH;        // B*N*H
  float* hbuf1 = cbuf + (size_t)BB * NN * HH;        // B*N*H

  // zero h0 and c (adjacent) — ws is poisoned 0xAA before every call
  hipMemsetAsync(hbuf0, 0, (size_t)2 * BB * NN * HH * sizeof(float), stream);

  k1_ax<<<dim3(BB * TT), 256, 0, stream>>>(adj, x, Ax);

  for (int t = 0; t < TT; ++t) {
    const float* hin = (t & 1) ? hbuf1 : hbuf0;
    float* hout = (t & 1) ? hbuf0 : hbuf1;
    k2_step<<<dim3(8, BB), K2_THR, 0, stream>>>(adj, Ax, gcnW, gcnb, hin, hout, cbuf, t);
  }
  // T=24 even: final h is in hbuf0
  k_tail<<<dim3(BB), 384, 0, stream>>>(x, hbuf0, tsi, gruWih, gruWhh, gru_bih, gru_bhh,
                                       fc2W, fc2b, fc3W, fc3b, fc4W, fc4b, fc5W, fc5b, out);
}

// Round 3
// 929.409 us; speedup vs baseline: 1.7712x; 1.3727x over previous
//
#include <hip/hip_runtime.h>
#include <math.h>

#define BB 32
#define TT 24
#define NN 256
#define FF 16
#define HH 128
#define G4 512  // 4*H

typedef _Float16 half8 __attribute__((ext_vector_type(8)));
typedef float f32x4 __attribute__((ext_vector_type(4)));

__device__ __forceinline__ float sigf(float x) { return 1.f / (1.f + __expf(-x)); }
__device__ __forceinline__ float tanhfast(float x) { return 1.f - 2.f / (__expf(2.f * x) + 1.f); }

// fp32 -> (hi, lo) fp16 split: v ~= hi + lo, residual ~2^-22 relative.
__device__ __forceinline__ void split8(const float* v, half8& hi, half8& lo) {
#pragma unroll
  for (int i = 0; i < 8; ++i) {
    const _Float16 h = (_Float16)v[i];
    hi[i] = h;
    lo[i] = (_Float16)(v[i] - (float)h);
  }
}

// ---------------------------------------------------------------------------
// K0a: pre-split+swizzle gcn_W into B-frag tiles.
// Wfrag[kc(5)][ct(32)][lane][8]: element W_op[k][n]:
//   kc<4 : gcnW[16 + kc*32 + k][ct*16 + n]   (h part, rows 16..143)
//   kc==4: k<16 ? gcnW[k][ct*16+n] : 0       (x part zero-padded to K=32)
// with k = (lane>>4)*8 + j, n = lane&15.
// ---------------------------------------------------------------------------
__global__ __launch_bounds__(64) void k0_wswz(const float* __restrict__ gcnW,
                                              _Float16* __restrict__ WfH,
                                              _Float16* __restrict__ WfL) {
  const int bid = blockIdx.x;  // kc*32 + ct, 0..159
  const int kc = bid >> 5, ct = bid & 31;
  const int l = threadIdx.x, quad = l >> 4, lo16 = l & 15;
  float v[8];
#pragma unroll
  for (int j = 0; j < 8; ++j) {
    const int k = quad * 8 + j;
    float val = 0.f;
    if (kc < 4) val = gcnW[(size_t)(16 + kc * 32 + k) * G4 + ct * 16 + lo16];
    else if (k < 16) val = gcnW[(size_t)k * G4 + ct * 16 + lo16];
    v[j] = val;
  }
  half8 hi, lo;
  split8(v, hi, lo);
  const size_t off = (size_t)bid * 512 + l * 8;
  *(half8*)&WfH[off] = hi;
  *(half8*)&WfL[off] = lo;
}

// ---------------------------------------------------------------------------
// K0b: pre-split+swizzle adjacency (adj[:, T-1]) into A-frag tiles.
// Afrag[b][nt16(16)][kc(8)][lane][8]: element adj[b][T-1][m][k],
//   m = nt16*16 + (lane&15), k = kc*32 + (lane>>4)*8 + j.
// ---------------------------------------------------------------------------
__global__ __launch_bounds__(64) void k0_aswz(const float* __restrict__ adj,
                                              _Float16* __restrict__ AfH,
                                              _Float16* __restrict__ AfL) {
  const int nt16 = blockIdx.x >> 3, kc = blockIdx.x & 7;
  const int b = blockIdx.y;
  const int l = threadIdx.x, quad = l >> 4, lo16 = l & 15;
  const float* src =
      adj + (((size_t)(b * TT + TT - 1)) * NN + nt16 * 16 + lo16) * NN + kc * 32 + quad * 8;
  const float4 v0 = *(const float4*)src;
  const float4 v1 = *(const float4*)(src + 4);
  float v[8] = {v0.x, v0.y, v0.z, v0.w, v1.x, v1.y, v1.z, v1.w};
  half8 hi, lo;
  split8(v, hi, lo);
  const size_t off = (((size_t)b * 16 + nt16) * 8 + kc) * 512 + l * 8;
  *(half8*)&AfH[off] = hi;
  *(half8*)&AfL[off] = lo;
}

// ---------------------------------------------------------------------------
// K1: Ax[b,t,n,f] = sum_j A[b,n,j] * x[b,t,j,f]   (fp32, parallel over b,t)
// ---------------------------------------------------------------------------
__global__ __launch_bounds__(256) void k1_ax(const float* __restrict__ adj,
                                             const float* __restrict__ x,
                                             float* __restrict__ Ax) {
  const int bt = blockIdx.x;
  const int b = bt / TT;
  const float* Abase = adj + ((size_t)(b * TT + (TT - 1)) * NN) * NN;
  const float* xbase = x + (size_t)bt * NN * FF;

  __shared__ float x_s[NN * FF];
  __shared__ float A_s[64 * 65];

  for (int i4 = threadIdx.x; i4 < (NN * FF) / 4; i4 += 256) {
    ((float4*)x_s)[i4] = ((const float4*)xbase)[i4];
  }
  const int rg = threadIdx.x >> 2;
  const int fg = threadIdx.x & 3;

  for (int rt = 0; rt < 4; ++rt) {
    float4 acc = make_float4(0.f, 0.f, 0.f, 0.f);
    for (int jc = 0; jc < 4; ++jc) {
      __syncthreads();
      for (int i = threadIdx.x; i < 64 * 64; i += 256) {
        const int r = i >> 6, j = i & 63;
        A_s[r * 65 + j] = Abase[(size_t)(rt * 64 + r) * NN + jc * 64 + j];
      }
      __syncthreads();
#pragma unroll 8
      for (int j = 0; j < 64; ++j) {
        const float a = A_s[rg * 65 + j];
        const float4 xv = *(const float4*)&x_s[(jc * 64 + j) * FF + fg * 4];
        acc.x += a * xv.x;
        acc.y += a * xv.y;
        acc.z += a * xv.z;
        acc.w += a * xv.w;
      }
    }
    *(float4*)&Ax[((size_t)bt * NN + rt * 64 + rg) * FF + fg * 4] = acc;
  }
}

// ---------------------------------------------------------------------------
// K2 (per step): MFMA fp16-split. grid (8 ntiles, B), 256 thr, 2 blocks/CU.
//   phase A: Ah(32x128) = A(32x256) @ h(256x128) — frags from global.
//   phase B: gates(32x512) = [Ah|Ax|0](32x160) @ Wfrag — Ah frags via LDS.
//   epilogue: LSTM pointwise; h -> fp16-split frag pair for next step.
// LDS region strides: Ah 164 (cols 0..127 Ah, 128..143 Ax, 144..159 zero),
// gates 516, h 130 — all uses sequential, one 64.5KB region.
// ---------------------------------------------------------------------------
__global__ __launch_bounds__(256, 2) void k2_step(
    const _Float16* __restrict__ AfH, const _Float16* __restrict__ AfL,
    const _Float16* __restrict__ WfH, const _Float16* __restrict__ WfL,
    const float* __restrict__ Ax, const float* __restrict__ gcnb,
    const _Float16* __restrict__ hInH, const _Float16* __restrict__ hInL,
    _Float16* __restrict__ hOutH, _Float16* __restrict__ hOutL,
    float* __restrict__ cbuf, float* __restrict__ h32, int t) {
  const int nt = blockIdx.x, b = blockIdx.y;
  const int n0 = nt * 32;
  const int tid = threadIdx.x;
  const int w = tid >> 6, l = tid & 63, quad = l >> 4, lo16 = l & 15;

  __shared__ float region[16512];

  // stage Ax -> region cols 128..143 (stride 164); zero pad cols 144..159
  {
    const int r = tid >> 3, f = (tid & 7) * 2;
    const float2 v = *(const float2*)&Ax[(((size_t)(b * TT + t)) * NN + n0 + r) * FF + f];
    *(float2*)&region[r * 164 + 128 + f] = v;
    *(float2*)&region[r * 164 + 144 + f] = make_float2(0.f, 0.f);
  }

  // ---- phase A: wave w -> hcol tiles {2w, 2w+1}, row tiles {0,1} ----
  f32x4 accA[2][2];
#pragma unroll
  for (int rt = 0; rt < 2; ++rt)
#pragma unroll
    for (int cc = 0; cc < 2; ++cc) accA[rt][cc] = (f32x4){0.f, 0.f, 0.f, 0.f};

  for (int kc = 0; kc < 8; ++kc) {
    half8 aH[2], aL[2], bH[2], bL[2];
#pragma unroll
    for (int rt = 0; rt < 2; ++rt) {
      const size_t off = (((size_t)b * 16 + 2 * nt + rt) * 8 + kc) * 512 + l * 8;
      aH[rt] = *(const half8*)&AfH[off];
      aL[rt] = *(const half8*)&AfL[off];
    }
#pragma unroll
    for (int cc = 0; cc < 2; ++cc) {
      const size_t off = (((size_t)b * 8 + kc) * 8 + (w * 2 + cc)) * 512 + l * 8;
      bH[cc] = *(const half8*)&hInH[off];
      bL[cc] = *(const half8*)&hInL[off];
    }
#pragma unroll
    for (int rt = 0; rt < 2; ++rt)
#pragma unroll
      for (int cc = 0; cc < 2; ++cc) {
        accA[rt][cc] = __builtin_amdgcn_mfma_f32_16x16x32_f16(aL[rt], bH[cc], accA[rt][cc], 0, 0, 0);
        accA[rt][cc] = __builtin_amdgcn_mfma_f32_16x16x32_f16(aH[rt], bL[cc], accA[rt][cc], 0, 0, 0);
        accA[rt][cc] = __builtin_amdgcn_mfma_f32_16x16x32_f16(aH[rt], bH[cc], accA[rt][cc], 0, 0, 0);
      }
  }
  // C-write Ah (C layout: col=lane&15, row=quad*4+reg) into region cols 0..127
#pragma unroll
  for (int rt = 0; rt < 2; ++rt)
#pragma unroll
    for (int cc = 0; cc < 2; ++cc)
#pragma unroll
      for (int r = 0; r < 4; ++r)
        region[(rt * 16 + quad * 4 + r) * 164 + (w * 2 + cc) * 16 + lo16] = accA[rt][cc][r];
  __syncthreads();  // B1: Ah + Ax staged

  // ---- phase B: wave w -> gate-col tiles 8w..8w+7, row tiles {0,1} ----
  f32x4 acc[2][8];
#pragma unroll
  for (int rt = 0; rt < 2; ++rt)
#pragma unroll
    for (int cc = 0; cc < 8; ++cc) acc[rt][cc] = (f32x4){0.f, 0.f, 0.f, 0.f};

  for (int kc = 0; kc < 5; ++kc) {
    half8 pH[2], pL[2];
#pragma unroll
    for (int rt = 0; rt < 2; ++rt) {
      const float* src = &region[(rt * 16 + lo16) * 164 + kc * 32 + quad * 8];
      const float4 v0 = *(const float4*)src;
      const float4 v1 = *(const float4*)(src + 4);
      float av[8] = {v0.x, v0.y, v0.z, v0.w, v1.x, v1.y, v1.z, v1.w};
      split8(av, pH[rt], pL[rt]);
    }
#pragma unroll
    for (int cc = 0; cc < 8; ++cc) {
      const size_t woff = ((size_t)(kc * 32 + w * 8 + cc)) * 512 + l * 8;
      const half8 wH = *(const half8*)&WfH[woff];
      const half8 wL = *(const half8*)&WfL[woff];
#pragma unroll
      for (int rt = 0; rt < 2; ++rt) {
        acc[rt][cc] = __builtin_amdgcn_mfma_f32_16x16x32_f16(pL[rt], wH, acc[rt][cc], 0, 0, 0);
        acc[rt][cc] = __builtin_amdgcn_mfma_f32_16x16x32_f16(pH[rt], wL, acc[rt][cc], 0, 0, 0);
        acc[rt][cc] = __builtin_amdgcn_mfma_f32_16x16x32_f16(pH[rt], wH, acc[rt][cc], 0, 0, 0);
      }
    }
  }
  __syncthreads();  // B2: all region (Ah) reads done
  // C-write gates, stride 516
#pragma unroll
  for (int rt = 0; rt < 2; ++rt)
#pragma unroll
    for (int cc = 0; cc < 8; ++cc)
#pragma unroll
      for (int r = 0; r < 4; ++r)
        region[(rt * 16 + quad * 4 + r) * 516 + (w * 8 + cc) * 16 + lo16] = acc[rt][cc][r];
  __syncthreads();  // B3: gates ready

  // ---- LSTM pointwise: thread -> (node = tid>>3, cols (tid&7)*16..+15) ----
  const int node = tid >> 3, hg = tid & 7;
  float hv[16];
  union F4 { float4 v; float a[4]; };
#pragma unroll
  for (int q = 0; q < 4; ++q) {
    const int col = hg * 16 + q * 4;
    F4 gi, gf, gg, go, c4, bi, bf, bg, bo, cn, hn;
    gi.v = *(const float4*)&region[node * 516 + col];
    gf.v = *(const float4*)&region[node * 516 + 128 + col];
    gg.v = *(const float4*)&region[node * 516 + 256 + col];
    go.v = *(const float4*)&region[node * 516 + 384 + col];
    bi.v = *(const float4*)&gcnb[col];
    bf.v = *(const float4*)&gcnb[128 + col];
    bg.v = *(const float4*)&gcnb[256 + col];
    bo.v = *(const float4*)&gcnb[384 + col];
    const size_t coff = ((size_t)b * NN + n0 + node) * HH + col;
    c4.v = *(const float4*)&cbuf[coff];
#pragma unroll
    for (int c = 0; c < 3 + 1; ++c) {
      const float iv = sigf(gi.a[c] + bi.a[c]);
      const float fv = sigf(gf.a[c] + bf.a[c]);
      const float gv = tanhfast(gg.a[c] + bg.a[c]);
      const float ov = sigf(go.a[c] + bo.a[c]);
      const float cnew = fv * c4.a[c] + iv * gv;
      cn.a[c] = cnew;
      hn.a[c] = ov * tanhfast(cnew);
      hv[q * 4 + c] = hn.a[c];
    }
    *(float4*)&cbuf[coff] = cn.v;
    if (nt == 0) *(float4*)&h32[((size_t)b * 32 + node) * HH + col] = hn.v;
  }
  __syncthreads();  // B4: gates reads done
  // h -> region, stride 130
#pragma unroll
  for (int j = 0; j < 8; ++j)
    *(float2*)&region[node * 130 + hg * 16 + 2 * j] = make_float2(hv[2 * j], hv[2 * j + 1]);
  __syncthreads();  // B5: h ready
  // hfrag production: wave w -> hcol tiles {2w, 2w+1}; this block = k-chunk nt
#pragma unroll
  for (int cc = 0; cc < 2; ++cc) {
    const int ct = w * 2 + cc;
    float v[8];
#pragma unroll
    for (int j = 0; j < 8; ++j) v[j] = region[(quad * 8 + j) * 130 + ct * 16 + lo16];
    half8 hh, hl;
    split8(v, hh, hl);
    const size_t off = (((size_t)b * 8 + nt) * 8 + ct) * 512 + l * 8;
    *(half8*)&hOutH[off] = hh;
    *(half8*)&hOutL[off] = hl;
  }
}

// ---------------------------------------------------------------------------
// Tail: GRU over t + fc5/fc2/fc3/fc4. grid = B, 384 threads.
// h32 layout: [b][node 0..31][128] (only node tile 0 is stored; tsi=5 < 32).
// ---------------------------------------------------------------------------
__global__ __launch_bounds__(384) void k_tail(
    const float* __restrict__ x, const float* __restrict__ h32,
    const int* __restrict__ tsi_p, const float* __restrict__ gruWih,
    const float* __restrict__ gruWhh, const float* __restrict__ gru_bih,
    const float* __restrict__ gru_bhh, const float* __restrict__ fc2W,
    const float* __restrict__ fc2b, const float* __restrict__ fc3W,
    const float* __restrict__ fc3b, const float* __restrict__ fc4W,
    const float* __restrict__ fc4b, const float* __restrict__ fc5W,
    const float* __restrict__ fc5b, float* __restrict__ out) {
  const int b = blockIdx.x;
  const int m = threadIdx.x;
  const int tsi = tsi_p[0];

  __shared__ float h_s[HH];
  __shared__ float xts[TT * FF];
  __shared__ float sum_s[384];
  __shared__ float gh_s[384];
  __shared__ float hc_s[2 * HH];
  __shared__ float xr_s[HH];
  __shared__ float f2_s[HH];
  __shared__ float f3_s[64];

  float4 whh[32];
#pragma unroll
  for (int q = 0; q < 32; ++q) whh[q] = *(const float4*)&gruWhh[(size_t)m * HH + q * 4];
  float4 wih[4];
#pragma unroll
  for (int q = 0; q < 4; ++q) wih[q] = *(const float4*)&gruWih[(size_t)m * FF + q * 4];
  const float bih_r = gru_bih[m];
  const float bhh_r = gru_bhh[m];

  {
    const int t = m >> 4, f = m & 15;
    xts[m] = x[(((size_t)b * TT + t) * NN + tsi) * FF + f];
  }
  if (m < HH) h_s[m] = 0.f;
  __syncthreads();

  for (int t = 0; t < TT; ++t) {
    float gi = bih_r;
#pragma unroll
    for (int q = 0; q < 4; ++q) {
      const float4 xv = *(const float4*)&xts[t * FF + q * 4];
      gi += wih[q].x * xv.x + wih[q].y * xv.y + wih[q].z * xv.z + wih[q].w * xv.w;
    }
    float gh = bhh_r;
#pragma unroll
    for (int q = 0; q < 32; ++q) {
      const float4 hv = *(const float4*)&h_s[q * 4];
      gh += whh[q].x * hv.x + whh[q].y * hv.y + whh[q].z * hv.z + whh[q].w * hv.w;
    }
    sum_s[m] = gi + gh;
    gh_s[m] = gh;
    __syncthreads();
    float hnew = 0.f;
    if (m < HH) {
      const float r = sigf(sum_s[m]);
      const float z = sigf(sum_s[HH + m]);
      const float ghn = gh_s[2 * HH + m];
      const float nn = tanhfast(sum_s[2 * HH + m] - ghn + r * ghn);
      hnew = (1.f - z) * nn + z * h_s[m];
    }
    __syncthreads();
    if (m < HH) h_s[m] = hnew;
    __syncthreads();
  }

  if (m < HH) {
    hc_s[m] = h_s[m];
    xr_s[m] = fmaxf(h32[((size_t)b * 32 + tsi) * HH + m], 0.f);
  }
  __syncthreads();
  if (m < HH) {
    float v = fc5b[m];
    const float* wr = fc5W + (size_t)m * HH;
#pragma unroll 8
    for (int k = 0; k < HH; k += 4) {
      const float4 wv = *(const float4*)(wr + k);
      v += xr_s[k] * wv.x + xr_s[k + 1] * wv.y + xr_s[k + 2] * wv.z + xr_s[k + 3] * wv.w;
    }
    hc_s[HH + m] = v;
  }
  __syncthreads();
  if (m < HH) {
    float v = fc2b[m];
    const float* wr = fc2W + (size_t)m * 2 * HH;
#pragma unroll 8
    for (int k = 0; k < 2 * HH; k += 4) {
      const float4 wv = *(const float4*)(wr + k);
      v += hc_s[k] * wv.x + hc_s[k + 1] * wv.y + hc_s[k + 2] * wv.z + hc_s[k + 3] * wv.w;
    }
    f2_s[m] = fmaxf(v, 0.f);
  }
  __syncthreads();
  if (m < 64) {
    float v = fc3b[m];
    const float* wr = fc3W + (size_t)m * HH;
#pragma unroll 8
    for (int k = 0; k < HH; k += 4) {
      const float4 wv = *(const float4*)(wr + k);
      v += f2_s[k] * wv.x + f2_s[k + 1] * wv.y + f2_s[k + 2] * wv.z + f2_s[k + 3] * wv.w;
    }
    f3_s[m] = fmaxf(v, 0.f);
  }
  __syncthreads();
  if (m < 24) {
    float v = fc4b[m];
    const float* wr = fc4W + (size_t)m * 64;
#pragma unroll
    for (int k = 0; k < 64; k += 4) {
      const float4 wv = *(const float4*)(wr + k);
      v += f3_s[k] * wv.x + f3_s[k + 1] * wv.y + f3_s[k + 2] * wv.z + f3_s[k + 3] * wv.w;
    }
    out[b * 24 + m] = v;
  }
}

// ---------------------------------------------------------------------------
extern "C" void kernel_launch(void* const* d_in, const int* in_sizes, int n_in,
                              void* d_out, int out_size, void* d_ws, size_t ws_size,
                              hipStream_t stream) {
  const float* x = (const float*)d_in[0];
  const float* adj = (const float*)d_in[1];
  const int* tsi = (const int*)d_in[2];
  const float* gcnW = (const float*)d_in[3];
  const float* gcnb = (const float*)d_in[4];
  const float* gruWih = (const float*)d_in[5];
  const float* gruWhh = (const float*)d_in[6];
  const float* gru_bih = (const float*)d_in[7];
  const float* gru_bhh = (const float*)d_in[8];
  const float* fc2W = (const float*)d_in[9];
  const float* fc2b = (const float*)d_in[10];
  const float* fc3W = (const float*)d_in[11];
  const float* fc3b = (const float*)d_in[12];
  const float* fc4W = (const float*)d_in[13];
  const float* fc4b = (const float*)d_in[14];
  const float* fc5W = (const float*)d_in[15];
  const float* fc5b = (const float*)d_in[16];
  float* out = (float*)d_out;

  // ws layout (all sizes in elements)
  float* Ax = (float*)d_ws;                           // 32*24*256*16   = 3,145,728 f
  float* cbuf = Ax + 3145728;                         // 32*256*128    = 1,048,576 f
  _Float16* hfH0 = (_Float16*)(cbuf + 1048576);       // 1,048,576 h
  _Float16* hfL0 = hfH0 + 1048576;                    // 1,048,576 h
  _Float16* hfH1 = hfL0 + 1048576;                    // 1,048,576 h
  _Float16* hfL1 = hfH1 + 1048576;                    // 1,048,576 h
  float* h32 = (float*)(hfL1 + 1048576);              // 32*32*128     = 131,072 f
  _Float16* AfH = (_Float16*)(h32 + 131072);          // 32*16*8*512   = 2,097,152 h
  _Float16* AfL = AfH + 2097152;                      // 2,097,152 h
  _Float16* WfH = AfL + 2097152;                      // 5*32*512      = 81,920 h
  _Float16* WfL = WfH + 81920;                        // 81,920 h

  // zero: cbuf (4MB) + hfH0/hfL0 (2MB+2MB) — contiguous, one memset
  hipMemsetAsync(cbuf, 0, 1048576 * 4 + 2 * 1048576 * 2, stream);

  k0_wswz<<<dim3(160), 64, 0, stream>>>(gcnW, WfH, WfL);
  k0_aswz<<<dim3(128, BB), 64, 0, stream>>>(adj, AfH, AfL);
  k1_ax<<<dim3(BB * TT), 256, 0, stream>>>(adj, x, Ax);

  for (int t = 0; t < TT; ++t) {
    const _Float16* hiH = (t & 1) ? hfH1 : hfH0;
    const _Float16* hiL = (t & 1) ? hfL1 : hfL0;
    _Float16* hoH = (t & 1) ? hfH0 : hfH1;
    _Float16* hoL = (t & 1) ? hfL0 : hfL1;
    k2_step<<<dim3(8, BB), 256, 0, stream>>>(AfH, AfL, WfH, WfL, Ax, gcnb, hiH, hiL, hoH, hoL,
                                             cbuf, h32, t);
  }
  k_tail<<<dim3(BB), 384, 0, stream>>>(x, h32, tsi, gruWih, gruWhh, gru_bih, gru_bhh, fc2W,
                                       fc2b, fc3W, fc3b, fc4W, fc4b, fc5W, fc5b, out);
}